// Round 7
// baseline (428.673 us; speedup 1.0000x reference)
//
#include <hip/hip_runtime.h>
#include <math.h>

#define NB 65536
#define ND 1280
#define NH 512
#define NT 4

typedef float f32x4 __attribute__((ext_vector_type(4)));
typedef float f32x2 __attribute__((ext_vector_type(2)));
typedef short s16x8 __attribute__((ext_vector_type(8)));
typedef unsigned int u32x2 __attribute__((ext_vector_type(2)));
typedef unsigned int u32x4 __attribute__((ext_vector_type(4)));
typedef unsigned long long ull;
typedef unsigned short u16;

static __device__ __forceinline__ unsigned f2bf1(float x) {
    union { float f; unsigned u; } v; v.f = x;
    return (v.u + 0x7fffu + ((v.u >> 16) & 1u)) >> 16;   // RNE f32 -> bf16 bits
}
static __device__ __forceinline__ unsigned packbf(float a, float b) {
    return f2bf1(a) | (f2bf1(b) << 16);
}
static __device__ __forceinline__ int swz(int a) {
    return a ^ (((a >> 7) & 7) << 4);
}
static __device__ __forceinline__ float gelu_exact(float x) {
    return 0.5f * x * (1.0f + erff(x * 0.70710678118654752f));
}

#define SCHEDB __builtin_amdgcn_sched_barrier(0)
#define WAITVM(N) do { asm volatile("s_waitcnt vmcnt(" #N ")" ::: "memory"); SCHEDB; } while (0)
#define WAITLG do { asm volatile("s_waitcnt lgkmcnt(0)" ::: "memory"); SCHEDB; } while (0)

// ---------------- W1 transpose+convert: [t][d][h] f32 -> [t][h][d] bf16 ----------------
__global__ __launch_bounds__(256) void transpose_kernel(const float* __restrict__ W1,
                                                        u16* __restrict__ Wt) {
    __shared__ float tile[64][65];
    int b = blockIdx.x;                 // 4 * 8 * 20 blocks
    int dt = b % 20; int r = b / 20; int ht = r & 7; int t = r >> 3;
    int d0 = dt * 64, h0 = ht * 64;
    int tid = threadIdx.x;
    const float* src = W1 + ((size_t)t * ND + d0) * NH + h0;
#pragma unroll
    for (int it = 0; it < 16; ++it) {
        int dl = it * 4 + (tid >> 6);
        tile[dl][tid & 63] = src[(size_t)dl * NH + (tid & 63)];
    }
    __syncthreads();
    int hl = tid >> 2, ds = (tid & 3) * 16;
    unsigned pk[8];
#pragma unroll
    for (int j = 0; j < 8; ++j)
        pk[j] = packbf(tile[ds + 2 * j][hl], tile[ds + 2 * j + 1][hl]);
    u16* dst = Wt + ((size_t)(t * NH + h0 + hl)) * ND + d0 + ds;
    *(u32x4*)dst = (u32x4){pk[0], pk[1], pk[2], pk[3]};
    *(u32x4*)(dst + 8) = (u32x4){pk[4], pk[5], pk[6], pk[7]};
}

// ---------------- bucketing (atomic-free counting sort) ----------------
__global__ __launch_bounds__(256) void count_kernel(const int* __restrict__ idx,
                                                    int* __restrict__ bc) {
    int tid = threadIdx.x;
    int i = blockIdx.x * 256 + tid;
    int t = idx[i];
    int lane = tid & 63, wave = tid >> 6;
    ull b0 = __ballot(t & 1);
    ull b1 = __ballot(t & 2);
    ull mask = ((t & 1) ? b0 : ~b0) & ((t & 2) ? b1 : ~b1);
    int rank = __popcll(mask & ((1ULL << lane) - 1ULL));
    __shared__ int lc[4][4];
    if (tid < 16) ((int*)lc)[tid] = 0;
    __syncthreads();
    if (rank == 0) lc[wave][t] = __popcll(mask);
    __syncthreads();
    if (tid < 4)
        bc[blockIdx.x * 4 + tid] = lc[0][tid] + lc[1][tid] + lc[2][tid] + lc[3][tid];
}

__global__ __launch_bounds__(256) void scan_kernel(const int* __restrict__ bc,
        int* __restrict__ counts, int* __restrict__ base, int* __restrict__ tmap) {
    __shared__ int segtot[64][4];
    __shared__ int segbase[64][4];
    __shared__ int ttot[4];
    int tid = threadIdx.x;
    int t = tid & 3, seg = tid >> 2;
    int s0 = bc[(seg * 4 + 0) * 4 + t];
    int s1 = bc[(seg * 4 + 1) * 4 + t];
    int s2 = bc[(seg * 4 + 2) * 4 + t];
    int s3 = bc[(seg * 4 + 3) * 4 + t];
    segtot[seg][t] = s0 + s1 + s2 + s3;
    __syncthreads();
    if (tid < 4) {
        int run = 0;
        for (int g = 0; g < 64; ++g) { segbase[g][tid] = run; run += segtot[g][tid]; }
        ttot[tid] = run;
        counts[tid] = run;
    }
    __syncthreads();
    if (tid == 0) {     // tile map: prefix over ceil(cnt_t/256)
        int s = 0;
        tmap[0] = 0;
        for (int u = 0; u < 4; ++u) { s += (ttot[u] + 255) >> 8; tmap[u + 1] = s; }
    }
    int toff = 0;
    for (int u = 0; u < 4; ++u) toff += (u < t) ? ttot[u] : 0;
    int run = toff + segbase[seg][t];
    base[(seg * 4 + 0) * 4 + t] = run; run += s0;
    base[(seg * 4 + 1) * 4 + t] = run; run += s1;
    base[(seg * 4 + 2) * 4 + t] = run; run += s2;
    base[(seg * 4 + 3) * 4 + t] = run;
}

__global__ __launch_bounds__(256) void scatter_kernel(const int* __restrict__ idx,
        const int* __restrict__ base, int* __restrict__ perm,
        const float* __restrict__ b2, float* __restrict__ out) {
    int tid = threadIdx.x;
    int i = blockIdx.x * 256 + tid;
    int t = idx[i];
    int lane = tid & 63, wave = tid >> 6;
    ull b0 = __ballot(t & 1);
    ull b1 = __ballot(t & 2);
    ull mask = ((t & 1) ? b0 : ~b0) & ((t & 2) ? b1 : ~b1);
    int rank = __popcll(mask & ((1ULL << lane) - 1ULL));
    __shared__ int lc[4][4];
    if (tid < 16) ((int*)lc)[tid] = 0;
    __syncthreads();
    if (rank == 0) lc[wave][t] = __popcll(mask);
    __syncthreads();
    int pre = 0;
#pragma unroll
    for (int w = 0; w < 4; ++w) pre += (w < wave) ? lc[w][t] : 0;
    perm[base[blockIdx.x * 4 + t] + pre + rank] = i;
    out[i] = b2[t];   // init for atomic fallback path
}

// ---------------- phase-split counted-vmcnt routed GEMM + fused epilogue ----------------
// BM=256 x BN=128, BK=64, 8 waves (4M x 2N), wave tile 64x64.
// A: f32 reg-staged one tile early -> cvt -> XOR-swizzled bf16 LDS (dbuf 2x32KB).
// B: direct-to-register frags from L2-resident pre-transposed Wt (parity double-set).
// Per tile: 2 phases {issue B-half | 4 ds_read A -> barrier -> lgkm0 -> prio1 ->
// 16 MFMA -> prio0 -> barrier}; tile-end: vmcnt(8) -> cvt+WRITEA -> issue A(kt+2)
// -> lgkm0 -> vmcnt(8) -> barrier.  In-flight never drains below 8 in steady state.
__global__ __launch_bounds__(512, 2) void gemm_8p(
        const float* __restrict__ feat, const u16* __restrict__ Wt,
        const float* __restrict__ b1, const float* __restrict__ w2,
        const int* __restrict__ perm, const int* __restrict__ counts,
        const int* __restrict__ tmap,
        float* __restrict__ partials, float* __restrict__ out, int use_partials) {
    __shared__ char smem[65536];        // A buf0 @0, buf1 @32768 (bf16 [256r][64k] swizzled)

    int bx = blockIdx.x;
    int r8 = bx & 7, m8 = bx >> 3;
    int ct = m8 & 3;
    int tau = (m8 >> 2) * 8 + r8;       // 4 ct-siblings of a row-tile adjacent per XCD
    if (tau >= tmap[4]) return;
    int t = 0;
#pragma unroll
    for (int u = 0; u < 3; ++u) t += (tau >= tmap[u + 1]) ? 1 : 0;
    int tile_m = tau - tmap[t];
    int cnt = counts[t];
    int tilebase = tile_m * 256;
    int off_t = 0;
    for (int u = 0; u < t; ++u) off_t += counts[u];

    int tid = threadIdx.x;
    int lane = tid & 63, wid = tid >> 6;
    int wr = wid >> 1, wc = wid & 1;    // 4M x 2N
    int rl = lane & 15, q0 = lane >> 4;
    int hc0 = ct * 128 + wc * 64;       // this wave's col base

    // ---- A staging: thread owns row tid>>1, k-half (tid&1)*32 ----
    int arow = tid >> 1;
    int grow = tilebase + arow; if (grow > cnt - 1) grow = cnt - 1;
    const float* asrc = feat + (size_t)(unsigned)perm[off_t + grow] * ND + (tid & 1) * 32;
    int akey = (arow & 7) << 4;
    int awoff[4];
#pragma unroll
    for (int c = 0; c < 4; ++c)
        awoff[c] = arow * 128 + (((tid & 1) * 64 + c * 16) ^ akey);

    // ---- A ds_read bases: row = wr*64 + mf*16 + rl; +mf*2048; kk=1 is ^64 ----
    int arb0 = (wr * 64 + rl) * 128 + ((q0 * 16) ^ ((rl & 7) << 4));
    int arb1 = arb0 ^ 64;

    // ---- B frag base: col = hc0 + nf*16 + rl, elem (t*NH+col)*ND + kk*32 + q0*8 ----
    const u16* bbase = Wt + (size_t)(t * NH + hc0 + rl) * ND + q0 * 8;

    f32x4 acc[4][4];
#pragma unroll
    for (int a = 0; a < 4; ++a)
#pragma unroll
        for (int b = 0; b < 4; ++b) acc[a][b] = (f32x4){0.f, 0.f, 0.f, 0.f};

    f32x4 apf[8];
    s16x8 bE[4][2], bO[4][2];

#define LOADA(KT) do {                                                          \
    _Pragma("unroll")                                                           \
    for (int j = 0; j < 8; ++j)                                                 \
        apf[j] = *(const f32x4*)(asrc + (KT) * 64 + j * 4);                     \
} while (0)

#define LOADBH(BS, KT, H) do {                                                  \
    BS[(H)*2+0][0] = *(const s16x8*)(bbase + (size_t)((H)*2+0)*16*ND + (KT)*64);      \
    BS[(H)*2+0][1] = *(const s16x8*)(bbase + (size_t)((H)*2+0)*16*ND + (KT)*64 + 32); \
    BS[(H)*2+1][0] = *(const s16x8*)(bbase + (size_t)((H)*2+1)*16*ND + (KT)*64);      \
    BS[(H)*2+1][1] = *(const s16x8*)(bbase + (size_t)((H)*2+1)*16*ND + (KT)*64 + 32); \
} while (0)

#define WRITEA(P) do {                                                          \
    char* ab_ = smem + (P) * 32768;                                             \
    _Pragma("unroll")                                                           \
    for (int c = 0; c < 4; ++c) {                                               \
        u32x4 v_ = (u32x4){packbf(apf[2*c][0],   apf[2*c][1]),                  \
                           packbf(apf[2*c][2],   apf[2*c][3]),                  \
                           packbf(apf[2*c+1][0], apf[2*c+1][1]),                \
                           packbf(apf[2*c+1][2], apf[2*c+1][3])};               \
        *(u32x4*)(ab_ + awoff[c]) = v_;                                         \
    }                                                                           \
} while (0)

#define PHASE(P, QD, BS) do {                                                   \
    char* ab_ = smem + (P) * 32768;                                             \
    s16x8 af00 = *(const s16x8*)(ab_ + arb0 + ((QD)*2+0)*2048);                 \
    s16x8 af01 = *(const s16x8*)(ab_ + arb1 + ((QD)*2+0)*2048);                 \
    s16x8 af10 = *(const s16x8*)(ab_ + arb0 + ((QD)*2+1)*2048);                 \
    s16x8 af11 = *(const s16x8*)(ab_ + arb1 + ((QD)*2+1)*2048);                 \
    __builtin_amdgcn_s_barrier();                                               \
    WAITLG;                                                                     \
    __builtin_amdgcn_s_setprio(1);                                              \
    _Pragma("unroll")                                                           \
    for (int nf = 0; nf < 4; ++nf) {                                            \
        acc[(QD)*2+0][nf] = __builtin_amdgcn_mfma_f32_16x16x32_bf16(af00, BS[nf][0], acc[(QD)*2+0][nf], 0,0,0); \
        acc[(QD)*2+0][nf] = __builtin_amdgcn_mfma_f32_16x16x32_bf16(af01, BS[nf][1], acc[(QD)*2+0][nf], 0,0,0); \
        acc[(QD)*2+1][nf] = __builtin_amdgcn_mfma_f32_16x16x32_bf16(af10, BS[nf][0], acc[(QD)*2+1][nf], 0,0,0); \
        acc[(QD)*2+1][nf] = __builtin_amdgcn_mfma_f32_16x16x32_bf16(af11, BS[nf][1], acc[(QD)*2+1][nf], 0,0,0); \
    }                                                                           \
    __builtin_amdgcn_s_setprio(0);                                              \
    __builtin_amdgcn_s_barrier();                                               \
} while (0)

// ENDMODE 0: steady; 1: kt==18 (no A-issue, full B drain); 2: kt==19 (nothing)
#define TILE(KT, P, BCUR, BNXT, STAGEB, ENDMODE) do {                           \
    if (STAGEB) { LOADBH(BNXT, (KT) + 1, 0); }                                  \
    PHASE(P, 0, BCUR);                                                          \
    if (STAGEB) { LOADBH(BNXT, (KT) + 1, 1); }                                  \
    PHASE(P, 1, BCUR);                                                          \
    if ((ENDMODE) == 0) {                                                       \
        WAITVM(8);              /* A(kt+1) landed; B(kt+1) still in flight */   \
        WRITEA((P) ^ 1);                                                        \
        LOADA((KT) + 2);                                                        \
        WAITLG;                 /* ds_writes visible before barrier */          \
        WAITVM(8);              /* B(kt+1) landed; A(kt+2) stays in flight */   \
        __builtin_amdgcn_s_barrier();                                           \
    } else if ((ENDMODE) == 1) {                                                \
        WAITVM(8);                                                              \
        WRITEA((P) ^ 1);                                                        \
        WAITLG;                                                                 \
        WAITVM(0);              /* only B(19) outstanding */                    \
        __builtin_amdgcn_s_barrier();                                           \
    }                                                                           \
} while (0)

    // ---- prologue ----
    LOADA(0);
    LOADBH(bE, 0, 0);
    LOADBH(bE, 0, 1);
    WAITVM(8);                 // A(0) done (8 oldest of 16)
    WRITEA(0);
    LOADA(1);
    WAITLG;
    WAITVM(8);                 // B(0) done; A(1) in flight
    __builtin_amdgcn_s_barrier();

    // ---- tiles 0..17 ----
#pragma unroll 1
    for (int kt = 0; kt < 18; kt += 2) {
        TILE(kt,     0, bE, bO, 1, 0);
        TILE(kt + 1, 1, bO, bE, 1, 0);
    }
    // ---- tiles 18, 19 ----
    TILE(18, 0, bE, bO, 1, 1);
    TILE(19, 1, bO, bE, 0, 2);

#undef TILE
#undef PHASE
#undef WRITEA
#undef LOADBH
#undef LOADA

    // ---- epilogue: +b1, exact GELU, *w2, reduce over this wave's 64 cols ----
    float part[4][4];
#pragma unroll
    for (int mf = 0; mf < 4; ++mf)
#pragma unroll
        for (int r = 0; r < 4; ++r) part[mf][r] = 0.f;
#pragma unroll
    for (int nf = 0; nf < 4; ++nf) {
        int h = hc0 + nf * 16 + rl;
        float b1v = b1[t * NH + h];
        float w2v = w2[t * NH + h];
#pragma unroll
        for (int mf = 0; mf < 4; ++mf)
#pragma unroll
            for (int r = 0; r < 4; ++r) {
                float v = acc[mf][nf][r] + b1v;
                part[mf][r] += gelu_exact(v) * w2v;
            }
    }
#pragma unroll
    for (int m = 1; m <= 8; m <<= 1)
#pragma unroll
        for (int mf = 0; mf < 4; ++mf)
#pragma unroll
            for (int r = 0; r < 4; ++r)
                part[mf][r] += __shfl_xor(part[mf][r], m, 64);

    if (rl == 0) {
        int slot = ct * 2 + wc;
#pragma unroll
        for (int mf = 0; mf < 4; ++mf)
#pragma unroll
            for (int r = 0; r < 4; ++r) {
                int row = wr * 64 + mf * 16 + q0 * 4 + r;
                int gr = tilebase + row;
                if (gr < cnt) {
                    int s = perm[off_t + gr];
                    if (use_partials)
                        partials[(size_t)s * 8 + slot] = part[mf][r];
                    else
                        atomicAdd(&out[s], part[mf][r]);
                }
            }
    }
}

// ---------------- fallback (no-Wt) path: R3 LDS kernel, strided f32 B ----------------
__global__ __launch_bounds__(256, 2) void gemm_fallback(
        const float* __restrict__ feat, const float* __restrict__ W1,
        const float* __restrict__ b1, const float* __restrict__ w2,
        const int* __restrict__ perm, const int* __restrict__ counts,
        float* __restrict__ partials, float* __restrict__ out, int use_partials) {
    __shared__ char smem[32768];
    int bx = blockIdx.x;
    int r8 = bx & 7, m8 = bx >> 3;
    int ct = m8 & 3, q = m8 >> 2;
    int g = q * 8 + r8;
    int t = g >> 9, tile_m = g & 511;
    int cnt = counts[t];
    int tilebase = tile_m * 128;
    if (tilebase >= cnt) return;
    int off_t = 0;
    for (int u = 0; u < t; ++u) off_t += counts[u];

    int tid = threadIdx.x;
    int lane = tid & 63, wave = tid >> 6;
    int wr = wave >> 1, wc = wave & 1;
    int hc0 = ct * 128;

    unsigned aoff[8];
#pragma unroll
    for (int i = 0; i < 8; ++i) {
        int r = tilebase + i * 16 + (tid >> 4);
        if (r > cnt - 1) r = cnt - 1;
        int s = perm[off_t + r];
        aoff[i] = (unsigned)s * ND + (tid & 15) * 4;
    }
    f32x4 acc[4][4];
#pragma unroll
    for (int a = 0; a < 4; ++a)
#pragma unroll
        for (int b = 0; b < 4; ++b) acc[a][b] = (f32x4){0.f, 0.f, 0.f, 0.f};
    f32x4 apf[8];
    int cpair = (tid & 63) * 2;
    int kkbase = tid >> 6;
    const float* wbase = W1 + (size_t)t * ND * NH + hc0 + cpair;
    f32x2 bpf[4][4];
    auto LOADA = [&](int k0) {
#pragma unroll
        for (int i = 0; i < 8; ++i)
            apf[i] = *(const f32x4*)(feat + aoff[i] + k0);
    };
    auto LOADB = [&](int k0) {
#pragma unroll
        for (int qq = 0; qq < 4; ++qq) {
            int d = k0 + (kkbase + qq * 4) * 4;
#pragma unroll
            for (int e = 0; e < 4; ++e)
                bpf[qq][e] = *(const f32x2*)(wbase + (size_t)(d + e) * NH);
        }
    };
    auto WRITEA = [&]() {
#pragma unroll
        for (int i = 0; i < 8; ++i) {
            int row = i * 16 + (tid >> 4);
            u32x2 v;
            v.x = packbf(apf[i][0], apf[i][1]);
            v.y = packbf(apf[i][2], apf[i][3]);
            *(u32x2*)(smem + swz(row * 128 + (tid & 15) * 8)) = v;
        }
    };
    auto WRITEB = [&]() {
#pragma unroll
        for (int qq = 0; qq < 4; ++qq) {
            int kk = kkbase + qq * 4;
#pragma unroll
            for (int j = 0; j < 2; ++j) {
                u32x2 v;
                v.x = packbf(bpf[qq][0][j], bpf[qq][1][j]);
                v.y = packbf(bpf[qq][2][j], bpf[qq][3][j]);
                *(u32x2*)(smem + 16384 + swz((cpair + j) * 128 + kk * 8)) = v;
            }
        }
    };
    auto COMPUTE_KS = [&](int ks) {
        int kbyte = ks * 64 + (lane >> 4) * 16;
        s16x8 af[4], bf[4];
#pragma unroll
        for (int f = 0; f < 4; ++f) {
            int rowA = wr * 64 + f * 16 + (lane & 15);
            af[f] = *(const s16x8*)(smem + swz(rowA * 128 + kbyte));
            int colB = wc * 64 + f * 16 + (lane & 15);
            bf[f] = *(const s16x8*)(smem + 16384 + swz(colB * 128 + kbyte));
        }
#pragma unroll
        for (int fm = 0; fm < 4; ++fm)
#pragma unroll
            for (int fn = 0; fn < 4; ++fn)
                acc[fm][fn] = __builtin_amdgcn_mfma_f32_16x16x32_bf16(
                    af[fm], bf[fn], acc[fm][fn], 0, 0, 0);
    };
    LOADA(0); LOADB(0);
    WRITEA(); WRITEB();
    __syncthreads();
#pragma unroll 1
    for (int kt = 0; kt < 20; ++kt) {
        bool nxt = (kt + 1 < 20);
        if (nxt) LOADA((kt + 1) * 64);
        COMPUTE_KS(0);
        if (nxt) LOADB((kt + 1) * 64);
        COMPUTE_KS(1);
        if (nxt) {
            __syncthreads();
            WRITEA(); WRITEB();
            __syncthreads();
        }
    }
    float part[4][4];
#pragma unroll
    for (int fm = 0; fm < 4; ++fm)
#pragma unroll
        for (int r = 0; r < 4; ++r) part[fm][r] = 0.f;
#pragma unroll
    for (int fn = 0; fn < 4; ++fn) {
        int h = hc0 + wc * 64 + fn * 16 + (lane & 15);
        float b1v = b1[t * NH + h];
        float w2v = w2[t * NH + h];
#pragma unroll
        for (int fm = 0; fm < 4; ++fm)
#pragma unroll
            for (int r = 0; r < 4; ++r) {
                float v = acc[fm][fn][r] + b1v;
                part[fm][r] += gelu_exact(v) * w2v;
            }
    }
#pragma unroll
    for (int m = 1; m <= 8; m <<= 1)
#pragma unroll
        for (int fm = 0; fm < 4; ++fm)
#pragma unroll
            for (int r = 0; r < 4; ++r)
                part[fm][r] += __shfl_xor(part[fm][r], m, 64);
    if ((lane & 15) == 0) {
        int slot = ct * 2 + wc;
#pragma unroll
        for (int fm = 0; fm < 4; ++fm)
#pragma unroll
            for (int r = 0; r < 4; ++r) {
                int row = wr * 64 + fm * 16 + (lane >> 4) * 4 + r;
                int gr = tilebase + row;
                if (gr < cnt) {
                    int s = perm[off_t + gr];
                    if (use_partials)
                        partials[(size_t)s * 8 + slot] = part[fm][r];
                    else
                        atomicAdd(&out[s], part[fm][r]);
                }
            }
    }
}

__global__ __launch_bounds__(256) void reduce_kernel(const float* __restrict__ partials,
        const int* __restrict__ idx, const float* __restrict__ b2,
        float* __restrict__ out) {
    int i = blockIdx.x * 256 + threadIdx.x;
    const float* p = partials + (size_t)i * 8;
    float s = b2[idx[i]];
#pragma unroll
    for (int j = 0; j < 8; ++j) s += p[j];
    out[i] = s;
}

extern "C" void kernel_launch(void* const* d_in, const int* in_sizes, int n_in,
                              void* d_out, int out_size, void* d_ws, size_t ws_size,
                              hipStream_t stream) {
    (void)in_sizes; (void)n_in; (void)out_size;
    const float* feat = (const float*)d_in[0];
    const int*   idx  = (const int*)d_in[1];
    const float* W1   = (const float*)d_in[2];
    const float* b1   = (const float*)d_in[3];
    const float* w2   = (const float*)d_in[4];
    const float* b2   = (const float*)d_in[5];
    float* out = (float*)d_out;

    char* ws = (char*)d_ws;
    int* counts  = (int*)ws;                                   // 64 B
    int* bc      = (int*)(ws + 64);                            // 4 KiB
    int* base    = (int*)(ws + 64 + 4096);                     // 4 KiB
    int* tmap    = (int*)(ws + 64 + 8192);                     // 64 B
    int* perm    = (int*)(ws + 128 + 8192);                    // 256 KiB
    float* partials = (float*)(ws + 128 + 8192 + (size_t)NB * 4);       // 2 MiB
    u16* Wt = (u16*)(ws + 128 + 8192 + (size_t)NB * 4 + (size_t)NB * 32); // 1.25 MiB
    size_t need_part = 128 + 8192 + (size_t)NB * 4 + (size_t)NB * 32;
    size_t need_full = need_part + (size_t)NT * ND * NH * 2;
    int use_partials = (ws_size >= need_part) ? 1 : 0;
    int use_wt = (ws_size >= need_full) ? 1 : 0;

    if (use_wt)
        transpose_kernel<<<NT * 8 * 20, 256, 0, stream>>>(W1, Wt);
    count_kernel<<<NB / 256, 256, 0, stream>>>(idx, bc);
    scan_kernel<<<1, 256, 0, stream>>>(bc, counts, base, tmap);
    scatter_kernel<<<NB / 256, 256, 0, stream>>>(idx, base, perm, b2, out);
    if (use_wt)
        gemm_8p<<<1056, 512, 0, stream>>>(feat, Wt, b1, w2, perm, counts, tmap,
                                          partials, out, use_partials);
    else
        gemm_fallback<<<8192, 256, 0, stream>>>(feat, W1, b1, w2, perm, counts,
                                                partials, out, use_partials);
    if (use_partials)
        reduce_kernel<<<NB / 256, 256, 0, stream>>>(partials, idx, b2, out);
}

// Round 8
// 277.931 us; speedup vs baseline: 1.5424x; 1.5424x over previous
//
#include <hip/hip_runtime.h>
#include <math.h>

#define NB 65536
#define ND 1280
#define NH 512
#define NT 4

typedef float f32x4 __attribute__((ext_vector_type(4)));
typedef float f32x2 __attribute__((ext_vector_type(2)));
typedef short s16x8 __attribute__((ext_vector_type(8)));
typedef unsigned int u32x2 __attribute__((ext_vector_type(2)));
typedef unsigned int u32x4 __attribute__((ext_vector_type(4)));
typedef unsigned long long ull;
typedef unsigned short u16;

static __device__ __forceinline__ unsigned f2bf1(float x) {
    union { float f; unsigned u; } v; v.f = x;
    return (v.u + 0x7fffu + ((v.u >> 16) & 1u)) >> 16;   // RNE f32 -> bf16 bits
}
static __device__ __forceinline__ unsigned packbf(float a, float b) {
    return f2bf1(a) | (f2bf1(b) << 16);
}
static __device__ __forceinline__ int swz(int a) {
    return a ^ (((a >> 7) & 7) << 4);
}
static __device__ __forceinline__ float gelu_exact(float x) {
    return 0.5f * x * (1.0f + erff(x * 0.70710678118654752f));
}

#define SCHEDB __builtin_amdgcn_sched_barrier(0)
#define WAITVM(N) do { asm volatile("s_waitcnt vmcnt(" #N ")" ::: "memory"); SCHEDB; } while (0)
#define WAITLG do { asm volatile("s_waitcnt lgkmcnt(0)" ::: "memory"); SCHEDB; } while (0)

// ---------------- W1 -> MFMA-fragment-ordered bf16 ----------------
// Wfrag[t][kt 20][cf 32][ks 2][lane 64][e 8]:
//   value = W1[t][k = kt*64 + ks*32 + (lane>>4)*8 + e][h = cf*16 + (lane&15)]
__global__ __launch_bounds__(256) void fragw_kernel(const float* __restrict__ W1,
                                                    u16* __restrict__ Wfrag) {
    __shared__ float tl[64][129];
    int b = blockIdx.x;                  // 320 = 4t * 20kt * 4cq
    int cq = b & 3, kt = (b >> 2) % 20, t = b / 80;
    int tid = threadIdx.x;
    const float* src = W1 + ((size_t)t * ND + kt * 64) * NH + cq * 128;
#pragma unroll
    for (int i = 0; i < 8; ++i) {
        int k = i * 8 + (tid >> 5), h4 = (tid & 31) * 4;
        f32x4 v = *(const f32x4*)(src + (size_t)k * NH + h4);
        tl[k][h4 + 0] = v[0]; tl[k][h4 + 1] = v[1];
        tl[k][h4 + 2] = v[2]; tl[k][h4 + 3] = v[3];
    }
    __syncthreads();
#pragma unroll
    for (int j = 0; j < 4; ++j) {
        int u = tid + 256 * j;
        int cfl = u >> 7, ks = (u >> 6) & 1, l = u & 63;
        int h = cfl * 16 + (l & 15);
        int kb = ks * 32 + (l >> 4) * 8;
        unsigned pk[4];
#pragma unroll
        for (int e = 0; e < 4; ++e)
            pk[e] = packbf(tl[kb + 2 * e][h], tl[kb + 2 * e + 1][h]);
        u16* dst = Wfrag + ((size_t)((t * 20 + kt) * 32 + cq * 8 + cfl) * 2 + ks) * 512 + l * 8;
        *(u32x4*)dst = (u32x4){pk[0], pk[1], pk[2], pk[3]};
    }
}

// ---------------- bucketing (atomic-free counting sort) ----------------
__global__ __launch_bounds__(256) void count_kernel(const int* __restrict__ idx,
                                                    int* __restrict__ bc) {
    int tid = threadIdx.x;
    int i = blockIdx.x * 256 + tid;
    int t = idx[i];
    int lane = tid & 63, wave = tid >> 6;
    ull b0 = __ballot(t & 1);
    ull b1 = __ballot(t & 2);
    ull mask = ((t & 1) ? b0 : ~b0) & ((t & 2) ? b1 : ~b1);
    int rank = __popcll(mask & ((1ULL << lane) - 1ULL));
    __shared__ int lc[4][4];
    if (tid < 16) ((int*)lc)[tid] = 0;
    __syncthreads();
    if (rank == 0) lc[wave][t] = __popcll(mask);
    __syncthreads();
    if (tid < 4)
        bc[blockIdx.x * 4 + tid] = lc[0][tid] + lc[1][tid] + lc[2][tid] + lc[3][tid];
}

__global__ __launch_bounds__(256) void scan_kernel(const int* __restrict__ bc,
        int* __restrict__ counts, int* __restrict__ base, int* __restrict__ tmap) {
    __shared__ int segtot[64][4];
    __shared__ int segbase[64][4];
    __shared__ int ttot[4];
    int tid = threadIdx.x;
    int t = tid & 3, seg = tid >> 2;
    int s0 = bc[(seg * 4 + 0) * 4 + t];
    int s1 = bc[(seg * 4 + 1) * 4 + t];
    int s2 = bc[(seg * 4 + 2) * 4 + t];
    int s3 = bc[(seg * 4 + 3) * 4 + t];
    segtot[seg][t] = s0 + s1 + s2 + s3;
    __syncthreads();
    if (tid < 4) {
        int run = 0;
        for (int g = 0; g < 64; ++g) { segbase[g][tid] = run; run += segtot[g][tid]; }
        ttot[tid] = run;
        counts[tid] = run;
    }
    __syncthreads();
    if (tid == 0) {     // tile map: prefix over ceil(cnt_t/128)
        int s = 0;
        tmap[0] = 0;
        for (int u = 0; u < 4; ++u) { s += (ttot[u] + 127) >> 7; tmap[u + 1] = s; }
    }
    int toff = 0;
    for (int u = 0; u < 4; ++u) toff += (u < t) ? ttot[u] : 0;
    int run = toff + segbase[seg][t];
    base[(seg * 4 + 0) * 4 + t] = run; run += s0;
    base[(seg * 4 + 1) * 4 + t] = run; run += s1;
    base[(seg * 4 + 2) * 4 + t] = run; run += s2;
    base[(seg * 4 + 3) * 4 + t] = run;
}

__global__ __launch_bounds__(256) void scatter_kernel(const int* __restrict__ idx,
        const int* __restrict__ base, int* __restrict__ perm,
        const float* __restrict__ b2, float* __restrict__ out) {
    int tid = threadIdx.x;
    int i = blockIdx.x * 256 + tid;
    int t = idx[i];
    int lane = tid & 63, wave = tid >> 6;
    ull b0 = __ballot(t & 1);
    ull b1 = __ballot(t & 2);
    ull mask = ((t & 1) ? b0 : ~b0) & ((t & 2) ? b1 : ~b1);
    int rank = __popcll(mask & ((1ULL << lane) - 1ULL));
    __shared__ int lc[4][4];
    if (tid < 16) ((int*)lc)[tid] = 0;
    __syncthreads();
    if (rank == 0) lc[wave][t] = __popcll(mask);
    __syncthreads();
    int pre = 0;
#pragma unroll
    for (int w = 0; w < 4; ++w) pre += (w < wave) ? lc[w][t] : 0;
    perm[base[blockIdx.x * 4 + t] + pre + rank] = i;
    out[i] = b2[t];   // init for atomic fallback path
}

// ---------------- routed GEMM: A in LDS (dbuf), B in registers ----------------
// 128x128 block, 4 waves (2x2), wave 64x64, BK=64, mfma 16x16x32.
// A: f32 reg-staged 1 tile early -> packbf -> swizzled LDS (R3's zero-conflict layout).
// B: one coalesced 1KB global load per fragment from Wfrag (L2-resident), 1 tile early.
// One s_barrier per K-tile; vmcnt never drains below 8 in steady state.
// LDS traffic per wave per tile: 8 ds_read_b128 + 4 ds_write_b128 (vs R3's 16+8+glds).
__global__ __launch_bounds__(256, 3) void gemm_rb(
        const float* __restrict__ feat, const u16* __restrict__ Wfrag,
        const float* __restrict__ b1, const float* __restrict__ w2,
        const int* __restrict__ perm, const int* __restrict__ counts,
        const int* __restrict__ tmap,
        float* __restrict__ partials, float* __restrict__ out, int use_partials) {
    __shared__ char smem[32768];        // A buf0 @0, buf1 @16384: bf16 [128r][64k] swizzled

    int bx = blockIdx.x;
    int r8 = bx & 7, m8 = bx >> 3;
    int ct = m8 & 3;
    int tau = (m8 >> 2) * 8 + r8;       // 4 ct-siblings adjacent per XCD slot
    if (tau >= tmap[4]) return;
    int t = 0;
#pragma unroll
    for (int u = 0; u < 3; ++u) t += (tau >= tmap[u + 1]) ? 1 : 0;
    int tile_m = tau - tmap[t];
    int cnt = counts[t];
    int tilebase = tile_m * 128;
    int off_t = 0;
    for (int u = 0; u < t; ++u) off_t += counts[u];

    int tid = threadIdx.x;
    int lane = tid & 63, wid = tid >> 6;
    int wr = wid >> 1, wc = wid & 1;
    int rl = lane & 15, q0 = lane >> 4;
    int hc0 = ct * 128 + wc * 64;

    // ---- A staging: thread owns (row = tid>>1, k-half = tid&1) ----
    int arow = tid >> 1;
    int grow = tilebase + arow; if (grow > cnt - 1) grow = cnt - 1;
    const float* asrc = feat + (size_t)(unsigned)perm[off_t + grow] * ND + (tid & 1) * 32;
    int awoff[4];
#pragma unroll
    for (int c = 0; c < 4; ++c)
        awoff[c] = arow * 128 + ((((tid & 1) * 4 + c) ^ (arow & 7)) << 4);

    // ---- A ds_read chunk bases: row = wr*64 + fm*16 + rl; chunk (ks*4+q0)^(rl&7) ----
    int arrow = (wr * 64 + rl) * 128;
    int arc0 = ((0 * 4 + q0) ^ (rl & 7)) << 4;   // ks=0
    int arc1 = ((1 * 4 + q0) ^ (rl & 7)) << 4;   // ks=1

    // ---- B fragment base: Wfrag[t][kt][ct*8+wc*4+fn][ks][lane][8] ----
    const u16* bb = Wfrag + (size_t)t * 655360
                  + (unsigned)((ct * 8 + wc * 4) * 1024) + lane * 8;

    f32x4 acc[4][4];
#pragma unroll
    for (int a = 0; a < 4; ++a)
#pragma unroll
        for (int b = 0; b < 4; ++b) acc[a][b] = (f32x4){0.f, 0.f, 0.f, 0.f};

    f32x4 apf[8];
    s16x8 bF[4][2];

#define LOADA(KT) do {                                                          \
    _Pragma("unroll")                                                           \
    for (int j = 0; j < 8; ++j)                                                 \
        apf[j] = *(const f32x4*)(asrc + (KT) * 64 + j * 4);                     \
} while (0)

#define LOADB(KT) do {                                                          \
    _Pragma("unroll")                                                           \
    for (int fn = 0; fn < 4; ++fn)                                              \
        _Pragma("unroll")                                                       \
        for (int ks = 0; ks < 2; ++ks)                                          \
            bF[fn][ks] = *(const s16x8*)(bb + (KT) * 32768 + fn * 1024 + ks * 512); \
} while (0)

#define WRITEA(P) do {                                                          \
    char* ab_ = smem + (P) * 16384;                                             \
    _Pragma("unroll")                                                           \
    for (int c = 0; c < 4; ++c) {                                               \
        u32x4 v_ = (u32x4){packbf(apf[2*c][0],   apf[2*c][1]),                  \
                           packbf(apf[2*c][2],   apf[2*c][3]),                  \
                           packbf(apf[2*c+1][0], apf[2*c+1][1]),                \
                           packbf(apf[2*c+1][2], apf[2*c+1][3])};               \
        *(u32x4*)(ab_ + awoff[c]) = v_;                                         \
    }                                                                           \
} while (0)

#define COMPUTE(P) do {                                                         \
    char* ab_ = smem + (P) * 16384;                                             \
    s16x8 af_[4];                                                               \
    __builtin_amdgcn_s_setprio(1);                                              \
    _Pragma("unroll")                                                           \
    for (int fm = 0; fm < 4; ++fm)                                              \
        af_[fm] = *(const s16x8*)(ab_ + arrow + fm * 2048 + arc0);              \
    _Pragma("unroll")                                                           \
    for (int fm = 0; fm < 4; ++fm)                                              \
        _Pragma("unroll")                                                       \
        for (int fn = 0; fn < 4; ++fn)                                          \
            acc[fm][fn] = __builtin_amdgcn_mfma_f32_16x16x32_bf16(              \
                af_[fm], bF[fn][0], acc[fm][fn], 0, 0, 0);                      \
    _Pragma("unroll")                                                           \
    for (int fm = 0; fm < 4; ++fm)                                              \
        af_[fm] = *(const s16x8*)(ab_ + arrow + fm * 2048 + arc1);              \
    _Pragma("unroll")                                                           \
    for (int fm = 0; fm < 4; ++fm)                                              \
        _Pragma("unroll")                                                       \
        for (int fn = 0; fn < 4; ++fn)                                          \
            acc[fm][fn] = __builtin_amdgcn_mfma_f32_16x16x32_bf16(              \
                af_[fm], bF[fn][1], acc[fm][fn], 0, 0, 0);                      \
    __builtin_amdgcn_s_setprio(0);                                              \
} while (0)

    // ---- prologue: LDS0 <- A(0); apf <- A(1) in flight; bF <- B(0) ----
    LOADA(0);
    LOADB(0);                         // outstanding A0:8 + B0:8
    WAITVM(8);                        // A0 landed
    WRITEA(0);
    LOADA(1);                         // B0:8 + A1:8
    WAITLG;
    WAITVM(8);                        // B0 landed; A1 in flight
    __builtin_amdgcn_s_barrier();

    // ---- steady: tiles 0..17 (2 per iteration, static buffer parity) ----
#pragma unroll 1
    for (int kt = 0; kt < 18; kt += 2) {
        COMPUTE(0);                   // A(kt) LDS0, B(kt) regs
        LOADB(kt + 1);                // A(kt+1):8 + B(kt+1):8
        WAITVM(8);                    // A(kt+1) landed
        WRITEA(1);
        LOADA(kt + 2);                // B(kt+1):8 + A(kt+2):8
        WAITLG;
        WAITVM(8);                    // B(kt+1) landed; A(kt+2) in flight
        __builtin_amdgcn_s_barrier();

        COMPUTE(1);
        LOADB(kt + 2);
        WAITVM(8);
        WRITEA(0);
        LOADA(kt + 3);
        WAITLG;
        WAITVM(8);
        __builtin_amdgcn_s_barrier();
    }
    // ---- tile 18 ----
    COMPUTE(0);
    LOADB(19);                        // A19:8 + B19:8
    WAITVM(8);                        // A19 landed
    WRITEA(1);
    WAITLG;
    WAITVM(0);                        // B19 landed
    __builtin_amdgcn_s_barrier();
    // ---- tile 19 ----
    COMPUTE(1);

#undef COMPUTE
#undef WRITEA
#undef LOADB
#undef LOADA

    // ---- epilogue: +b1, exact GELU, *w2, reduce over this wave's 64 cols ----
    float part[4][4];
#pragma unroll
    for (int mf = 0; mf < 4; ++mf)
#pragma unroll
        for (int r = 0; r < 4; ++r) part[mf][r] = 0.f;
#pragma unroll
    for (int nf = 0; nf < 4; ++nf) {
        int h = hc0 + nf * 16 + rl;
        float b1v = b1[t * NH + h];
        float w2v = w2[t * NH + h];
#pragma unroll
        for (int mf = 0; mf < 4; ++mf)
#pragma unroll
            for (int r = 0; r < 4; ++r) {
                float v = acc[mf][nf][r] + b1v;
                part[mf][r] += gelu_exact(v) * w2v;
            }
    }
#pragma unroll
    for (int m = 1; m <= 8; m <<= 1)
#pragma unroll
        for (int mf = 0; mf < 4; ++mf)
#pragma unroll
            for (int r = 0; r < 4; ++r)
                part[mf][r] += __shfl_xor(part[mf][r], m, 64);

    if (rl == 0) {
        int slot = ct * 2 + wc;
#pragma unroll
        for (int mf = 0; mf < 4; ++mf)
#pragma unroll
            for (int r = 0; r < 4; ++r) {
                int row = wr * 64 + mf * 16 + q0 * 4 + r;
                int gr = tilebase + row;
                if (gr < cnt) {
                    int s = perm[off_t + gr];
                    if (use_partials)
                        partials[(size_t)s * 8 + slot] = part[mf][r];
                    else
                        atomicAdd(&out[s], part[mf][r]);
                }
            }
    }
}

// ---------------- fallback (no-ws) path: R3 LDS kernel, strided f32 B ----------------
__global__ __launch_bounds__(256, 2) void gemm_fallback(
        const float* __restrict__ feat, const float* __restrict__ W1,
        const float* __restrict__ b1, const float* __restrict__ w2,
        const int* __restrict__ perm, const int* __restrict__ counts,
        float* __restrict__ partials, float* __restrict__ out, int use_partials) {
    __shared__ char smem[32768];
    int bx = blockIdx.x;
    int r8 = bx & 7, m8 = bx >> 3;
    int ct = m8 & 3, q = m8 >> 2;
    int g = q * 8 + r8;
    int t = g >> 9, tile_m = g & 511;
    int cnt = counts[t];
    int tilebase = tile_m * 128;
    if (tilebase >= cnt) return;
    int off_t = 0;
    for (int u = 0; u < t; ++u) off_t += counts[u];

    int tid = threadIdx.x;
    int lane = tid & 63, wave = tid >> 6;
    int wr = wave >> 1, wc = wave & 1;
    int hc0 = ct * 128;

    unsigned aoff[8];
#pragma unroll
    for (int i = 0; i < 8; ++i) {
        int r = tilebase + i * 16 + (tid >> 4);
        if (r > cnt - 1) r = cnt - 1;
        int s = perm[off_t + r];
        aoff[i] = (unsigned)s * ND + (tid & 15) * 4;
    }
    f32x4 acc[4][4];
#pragma unroll
    for (int a = 0; a < 4; ++a)
#pragma unroll
        for (int b = 0; b < 4; ++b) acc[a][b] = (f32x4){0.f, 0.f, 0.f, 0.f};
    f32x4 apf[8];
    int cpair = (tid & 63) * 2;
    int kkbase = tid >> 6;
    const float* wbase = W1 + (size_t)t * ND * NH + hc0 + cpair;
    f32x2 bpf[4][4];
    auto LOADA = [&](int k0) {
#pragma unroll
        for (int i = 0; i < 8; ++i)
            apf[i] = *(const f32x4*)(feat + aoff[i] + k0);
    };
    auto LOADB = [&](int k0) {
#pragma unroll
        for (int qq = 0; qq < 4; ++qq) {
            int d = k0 + (kkbase + qq * 4) * 4;
#pragma unroll
            for (int e = 0; e < 4; ++e)
                bpf[qq][e] = *(const f32x2*)(wbase + (size_t)(d + e) * NH);
        }
    };
    auto WRITEA = [&]() {
#pragma unroll
        for (int i = 0; i < 8; ++i) {
            int row = i * 16 + (tid >> 4);
            u32x2 v;
            v.x = packbf(apf[i][0], apf[i][1]);
            v.y = packbf(apf[i][2], apf[i][3]);
            *(u32x2*)(smem + swz(row * 128 + (tid & 15) * 8)) = v;
        }
    };
    auto WRITEB = [&]() {
#pragma unroll
        for (int qq = 0; qq < 4; ++qq) {
            int kk = kkbase + qq * 4;
#pragma unroll
            for (int j = 0; j < 2; ++j) {
                u32x2 v;
                v.x = packbf(bpf[qq][0][j], bpf[qq][1][j]);
                v.y = packbf(bpf[qq][2][j], bpf[qq][3][j]);
                *(u32x2*)(smem + 16384 + swz((cpair + j) * 128 + kk * 8)) = v;
            }
        }
    };
    auto COMPUTE_KS = [&](int ks) {
        int kbyte = ks * 64 + (lane >> 4) * 16;
        s16x8 af[4], bf[4];
#pragma unroll
        for (int f = 0; f < 4; ++f) {
            int rowA = wr * 64 + f * 16 + (lane & 15);
            af[f] = *(const s16x8*)(smem + swz(rowA * 128 + kbyte));
            int colB = wc * 64 + f * 16 + (lane & 15);
            bf[f] = *(const s16x8*)(smem + 16384 + swz(colB * 128 + kbyte));
        }
#pragma unroll
        for (int fm = 0; fm < 4; ++fm)
#pragma unroll
            for (int fn = 0; fn < 4; ++fn)
                acc[fm][fn] = __builtin_amdgcn_mfma_f32_16x16x32_bf16(
                    af[fm], bf[fn], acc[fm][fn], 0, 0, 0);
    };
    LOADA(0); LOADB(0);
    WRITEA(); WRITEB();
    __syncthreads();
#pragma unroll 1
    for (int kt = 0; kt < 20; ++kt) {
        bool nxt = (kt + 1 < 20);
        if (nxt) LOADA((kt + 1) * 64);
        COMPUTE_KS(0);
        if (nxt) LOADB((kt + 1) * 64);
        COMPUTE_KS(1);
        if (nxt) {
            __syncthreads();
            WRITEA(); WRITEB();
            __syncthreads();
        }
    }
    float part[4][4];
#pragma unroll
    for (int fm = 0; fm < 4; ++fm)
#pragma unroll
        for (int r = 0; r < 4; ++r) part[fm][r] = 0.f;
#pragma unroll
    for (int fn = 0; fn < 4; ++fn) {
        int h = hc0 + wc * 64 + fn * 16 + (lane & 15);
        float b1v = b1[t * NH + h];
        float w2v = w2[t * NH + h];
#pragma unroll
        for (int fm = 0; fm < 4; ++fm)
#pragma unroll
            for (int r = 0; r < 4; ++r) {
                float v = acc[fm][fn][r] + b1v;
                part[fm][r] += gelu_exact(v) * w2v;
            }
    }
#pragma unroll
    for (int m = 1; m <= 8; m <<= 1)
#pragma unroll
        for (int fm = 0; fm < 4; ++fm)
#pragma unroll
            for (int r = 0; r < 4; ++r)
                part[fm][r] += __shfl_xor(part[fm][r], m, 64);
    if ((lane & 15) == 0) {
        int slot = ct * 2 + wc;
#pragma unroll
        for (int fm = 0; fm < 4; ++fm)
#pragma unroll
            for (int r = 0; r < 4; ++r) {
                int row = wr * 64 + fm * 16 + (lane >> 4) * 4 + r;
                int gr = tilebase + row;
                if (gr < cnt) {
                    int s = perm[off_t + gr];
                    if (use_partials)
                        partials[(size_t)s * 8 + slot] = part[fm][r];
                    else
                        atomicAdd(&out[s], part[fm][r]);
                }
            }
    }
}

__global__ __launch_bounds__(256) void reduce_kernel(const float* __restrict__ partials,
        const int* __restrict__ idx, const float* __restrict__ b2,
        float* __restrict__ out) {
    int i = blockIdx.x * 256 + threadIdx.x;
    const float* p = partials + (size_t)i * 8;
    float s = b2[idx[i]];
#pragma unroll
    for (int j = 0; j < 8; ++j) s += p[j];
    out[i] = s;
}

extern "C" void kernel_launch(void* const* d_in, const int* in_sizes, int n_in,
                              void* d_out, int out_size, void* d_ws, size_t ws_size,
                              hipStream_t stream) {
    (void)in_sizes; (void)n_in; (void)out_size;
    const float* feat = (const float*)d_in[0];
    const int*   idx  = (const int*)d_in[1];
    const float* W1   = (const float*)d_in[2];
    const float* b1   = (const float*)d_in[3];
    const float* w2   = (const float*)d_in[4];
    const float* b2   = (const float*)d_in[5];
    float* out = (float*)d_out;

    char* ws = (char*)d_ws;
    int* counts  = (int*)ws;                                   // 64 B
    int* bc      = (int*)(ws + 64);                            // 4 KiB
    int* base    = (int*)(ws + 64 + 4096);                     // 4 KiB
    int* tmap    = (int*)(ws + 64 + 8192);                     // 64 B
    int* perm    = (int*)(ws + 128 + 8192);                    // 256 KiB
    float* partials = (float*)(ws + 128 + 8192 + (size_t)NB * 4);       // 2 MiB
    u16* Wfrag = (u16*)(ws + 128 + 8192 + (size_t)NB * 4 + (size_t)NB * 32); // 5.25 MiB
    size_t need_part = 128 + 8192 + (size_t)NB * 4 + (size_t)NB * 32;
    size_t need_full = need_part + (size_t)NT * ND * NH * 2;
    int use_partials = (ws_size >= need_part) ? 1 : 0;
    int use_wt = (ws_size >= need_full) ? 1 : 0;

    if (use_wt)
        fragw_kernel<<<320, 256, 0, stream>>>(W1, Wfrag);
    count_kernel<<<NB / 256, 256, 0, stream>>>(idx, bc);
    scan_kernel<<<1, 256, 0, stream>>>(bc, counts, base, tmap);
    scatter_kernel<<<NB / 256, 256, 0, stream>>>(idx, base, perm, b2, out);
    if (use_wt)
        gemm_rb<<<2080, 256, 0, stream>>>(feat, Wfrag, b1, w2, perm, counts, tmap,
                                          partials, out, use_partials);
    else
        gemm_fallback<<<8192, 256, 0, stream>>>(feat, W1, b1, w2, perm, counts,
                                                partials, out, use_partials);
    if (use_partials)
        reduce_kernel<<<NB / 256, 256, 0, stream>>>(partials, idx, b2, out);
}